// Round 8
// baseline (210.593 us; speedup 1.0000x reference)
//
#include <hip/hip_runtime.h>
#include <math.h>

#define L_SEQ 384
#define E_DIM 512
#define NHEAD 8
#define NBH   16
#define HD    64
#define JSPLIT 12
#define JTILE  32          // L_SEQ / JSPLIT
#define PROJ_ELEMS (NBH * L_SEQ * HD)   // 393216

typedef __attribute__((ext_vector_type(8))) __bf16 bf16x8;
typedef __attribute__((ext_vector_type(4))) float f32x4;

__device__ __forceinline__ float uniform_f(float v) {
  return __uint_as_float(__builtin_amdgcn_readfirstlane(__float_as_uint(v)));
}

__device__ __forceinline__ unsigned f2bf(float f) {   // RNE float->bf16 bits
  unsigned u = __float_as_uint(f);
  return (u + 0x7FFFu + ((u >> 16) & 1u)) >> 16;
}

__device__ __forceinline__ bf16x8 cvt8(float4 a, float4 b) {  // 8 fp32 -> bf16x8
  union { bf16x8 v; unsigned u[4]; } r;
  r.u[0] = f2bf(a.x) | (f2bf(a.y) << 16);
  r.u[1] = f2bf(a.z) | (f2bf(a.w) << 16);
  r.u[2] = f2bf(b.x) | (f2bf(b.y) << 16);
  r.u[3] = f2bf(b.z) | (f2bf(b.w) << 16);
  return r.v;
}

// sum over the 4 lanes of each quad — pure-VALU DPP quad_perm butterfly
__device__ __forceinline__ float quad_sum(float x) {
  x += __int_as_float(__builtin_amdgcn_mov_dpp(__float_as_int(x), 0xB1, 0xF, 0xF, 0)); // xor 1
  x += __int_as_float(__builtin_amdgcn_mov_dpp(__float_as_int(x), 0x4E, 0xF, 0xF, 0)); // xor 2
  return x;
}

// ---------------------------------------------------------------------------
// bf16 MFMA GEMM, in-register fp32->bf16 conversion. C = A @ B^T.
// (R6-proven structure. R7 lesson: do NOT fold slab reduction in here —
//  24 extra L2 loads + 96 FMAs per k-step at ~1 block/CU cost ~50 us.)
// Block 256 = 4 waves; tile 64(m)x64(n); wave = 16-row m-strip, 4 n-tiles.
// A: fp32 (abf=0) or bf16 (abf=1) MxK row-major; Bm: NxK fp32 row-major.
// mode 0: C[m*N+f]; mode 1: head-scatter C[((b*8+h)*L+l)*64+d].
// ---------------------------------------------------------------------------
__global__ __launch_bounds__(256) void gemm_mfma(
    const void* __restrict__ Av, const float* __restrict__ B0,
    const float* __restrict__ B1, const float* __restrict__ B2,
    float* __restrict__ C0, float* __restrict__ C1, float* __restrict__ C2,
    int M, int N, int K, int mode, int abf)
{
  const int z = blockIdx.z;
  const float* Bm = (z == 0) ? B0 : (z == 1) ? B1 : B2;
  float* Cp = (z == 0) ? C0 : (z == 1) ? C1 : C2;

  const int tid = threadIdx.x;
  const int wave = tid >> 6, lane = tid & 63;
  const int m0 = blockIdx.y * 64 + wave * 16;
  const int n0 = blockIdx.x * 64;
  const int mr = lane & 15, quad = lane >> 4;

  f32x4 acc[4];
  #pragma unroll
  for (int nt = 0; nt < 4; ++nt) acc[nt] = (f32x4){0.f, 0.f, 0.f, 0.f};

  const float* apf = (const float*)Av + (size_t)(m0 + mr) * K + quad * 8;
  const __bf16* apb = (const __bf16*)Av + (size_t)(m0 + mr) * K + quad * 8;
  const float* bp = Bm + (size_t)(n0 + mr) * K + quad * 8;

  #pragma unroll 2
  for (int k0 = 0; k0 < K; k0 += 32) {
    bf16x8 a;
    if (abf) {
      a = *(const bf16x8*)(apb + k0);
    } else {
      float4 a0 = *(const float4*)(apf + k0);
      float4 a1 = *(const float4*)(apf + k0 + 4);
      a = cvt8(a0, a1);
    }
    #pragma unroll
    for (int nt = 0; nt < 4; ++nt) {
      const float* bq = bp + (size_t)nt * 16 * K + k0;
      float4 b0 = *(const float4*)(bq);
      float4 b1 = *(const float4*)(bq + 4);
      bf16x8 b = cvt8(b0, b1);
      acc[nt] = __builtin_amdgcn_mfma_f32_16x16x32_bf16(a, b, acc[nt], 0, 0, 0);
    }
  }

  #pragma unroll
  for (int nt = 0; nt < 4; ++nt) {
    int n = n0 + nt * 16 + mr;
    #pragma unroll
    for (int r = 0; r < 4; ++r) {
      int m = m0 + quad * 4 + r;
      if (mode == 0) {
        Cp[(size_t)m * N + n] = acc[nt][r];
      } else {
        int b = m / L_SEQ, l = m % L_SEQ;
        int h = n >> 6, d = n & 63;
        Cp[((size_t)(b * NHEAD + h) * L_SEQ + l) * HD + d] = acc[nt][r];
      }
    }
  }
}

// ---------------------------------------------------------------------------
// Fused pairwise core (round-5 proven, 83 us).
// Block 128 = 32 i x 4 lanes, 4 atoms/thread; grid (12, 12, 16).
// Prenormalized q/k (|ham(q,k)|=|q||k|); gate reduce = DPP quad butterflies;
// plain slab stores, no fences, no atomics.
// ---------------------------------------------------------------------------
__global__ __launch_bounds__(128, 4) void berry_main(
    const float* __restrict__ Q, const float* __restrict__ K,
    const float* __restrict__ V, const float* __restrict__ dde_w,
    const float* __restrict__ dde_b, float* __restrict__ CTXS)
{
  __shared__ float kt[JTILE][HD];   // normalized k atoms
  __shared__ float vt[JTILE][HD];   // raw v

  const int tid = threadIdx.x;
  const int bh = blockIdx.z;
  const int i = blockIdx.y * 32 + (tid >> 2);
  const int ag = tid & 3;                 // lane-in-quad: atoms ag*4 .. ag*4+3
  const int js = blockIdx.x;
  const int j0 = js * JTILE;

  // gate params in SGPRs; mean over 16 atoms folded into weights
  float gw[16];
  #pragma unroll
  for (int t = 0; t < 16; ++t) gw[t] = uniform_f(dde_w[t]) * 0.0625f;
  const float gb0 = uniform_f(dde_b[0]), gb1 = uniform_f(dde_b[1]);
  const float gb2 = uniform_f(dde_b[2]), gb3 = uniform_f(dde_b[3]);

  float4 qa[4], ctx[4];
  const float* qp = Q + ((size_t)(bh * L_SEQ + i) * HD + ag * 16);
  #pragma unroll
  for (int t = 0; t < 4; ++t) {
    float4 q = ((const float4*)qp)[t];
    float d = q.x * q.x + q.y * q.y + q.z * q.z + q.w * q.w;
    float r = __builtin_amdgcn_rsqf(fmaxf(d, 1e-30f));
    qa[t].x = q.x * r; qa[t].y = q.y * r; qa[t].z = q.z * r; qa[t].w = q.w * r;
    ctx[t] = make_float4(0.f, 0.f, 0.f, 0.f);
  }

  // stage K (normalized per atom) + V: 32 j x 16 atoms = 512, 4/thread
  #pragma unroll
  for (int p = 0; p < 4; ++p) {
    int idx = tid + p * 128;
    int jj = idx >> 4, at = idx & 15;
    size_t g = (size_t)(bh * L_SEQ + j0 + jj) * HD + at * 4;
    float4 kq = *(const float4*)(K + g);
    float d = kq.x * kq.x + kq.y * kq.y + kq.z * kq.z + kq.w * kq.w;
    float r = __builtin_amdgcn_rsqf(fmaxf(d, 1e-30f));
    kq.x *= r; kq.y *= r; kq.z *= r; kq.w *= r;
    *(float4*)&kt[jj][at * 4] = kq;
    *(float4*)&vt[jj][at * 4] = *(const float4*)(V + g);
  }
  __syncthreads();

  for (int jj = 0; jj < JTILE; ++jj) {
    float4 h[4];
    float gsx = 0.f, gsy = 0.f, gsz = 0.f, gsw = 0.f;
    #pragma unroll
    for (int a = 0; a < 4; ++a) {
      float4 kq = *(const float4*)&kt[jj][ag * 16 + a * 4];
      h[a].x = qa[a].x * kq.x - qa[a].y * kq.y - qa[a].z * kq.z - qa[a].w * kq.w;
      h[a].y = qa[a].x * kq.y + qa[a].y * kq.x + qa[a].z * kq.w - qa[a].w * kq.z;
      h[a].z = qa[a].x * kq.z - qa[a].y * kq.w + qa[a].z * kq.x + qa[a].w * kq.y;
      h[a].w = qa[a].x * kq.w + qa[a].y * kq.z - qa[a].z * kq.y + qa[a].w * kq.x;
      gsx += h[a].x; gsy += h[a].y; gsz += h[a].z; gsw += h[a].w;
    }
    gsx = quad_sum(gsx); gsy = quad_sum(gsy);
    gsz = quad_sum(gsz); gsw = quad_sum(gsw);

    float t0 = gb0 + gw[0]  * gsx + gw[1]  * gsy + gw[2]  * gsz + gw[3]  * gsw;
    float t1 = gb1 + gw[4]  * gsx + gw[5]  * gsy + gw[6]  * gsz + gw[7]  * gsw;
    float t2 = gb2 + gw[8]  * gsx + gw[9]  * gsy + gw[10] * gsz + gw[11] * gsw;
    float t3 = gb3 + gw[12] * gsx + gw[13] * gsy + gw[14] * gsz + gw[15] * gsw;
    float4 g;
    g.x = __builtin_amdgcn_rcpf(1.f + __expf(-t0));
    g.y = __builtin_amdgcn_rcpf(1.f + __expf(-t1));
    g.z = __builtin_amdgcn_rcpf(1.f + __expf(-t2));
    g.w = __builtin_amdgcn_rcpf(1.f + __expf(-t3));

    #pragma unroll
    for (int a = 0; a < 4; ++a) {
      float4 vq = *(const float4*)&vt[jj][ag * 16 + a * 4];
      float sx = h[a].x * g.x, sy = h[a].y * g.y;
      float sz = h[a].z * g.z, sw = h[a].w * g.w;
      ctx[a].x += sx * vq.x - sy * vq.y - sz * vq.z - sw * vq.w;
      ctx[a].y += sx * vq.y + sy * vq.x + sz * vq.w - sw * vq.z;
      ctx[a].z += sx * vq.z - sy * vq.w + sz * vq.x + sw * vq.y;
      ctx[a].w += sx * vq.w + sy * vq.z - sz * vq.y + sw * vq.x;
    }
  }

  // plain stores into this j-chunk's slab
  float* cp = CTXS + ((size_t)(js * NBH + bh) * L_SEQ + i) * HD + ag * 16;
  #pragma unroll
  for (int t = 0; t < 4; ++t) ((float4*)cp)[t] = ctx[t];
}

// ---------------------------------------------------------------------------
// Sum the JSPLIT ctx slabs, transpose heads into (b,l,e), emit bf16
// (round-5 proven).
// ---------------------------------------------------------------------------
__global__ __launch_bounds__(256) void ctx_reduce(
    const float* __restrict__ CTXS, unsigned short* __restrict__ CTXB)
{
  int idx = blockIdx.x * 256 + threadIdx.x;      // over 98304 float4 groups
  int row = idx >> 4;                            // bh*L + i
  int d0 = (idx & 15) * 4;
  float4 s = make_float4(0.f, 0.f, 0.f, 0.f);
  #pragma unroll
  for (int js = 0; js < JSPLIT; ++js) {
    float4 v = *(const float4*)&CTXS[(size_t)js * PROJ_ELEMS + (size_t)row * HD + d0];
    s.x += v.x; s.y += v.y; s.z += v.z; s.w += v.w;
  }
  int bh = row / L_SEQ, i = row - bh * L_SEQ;
  int b = bh >> 3, h = bh & 7;
  unsigned lo = f2bf(s.x) | (f2bf(s.y) << 16);
  unsigned hi = f2bf(s.z) | (f2bf(s.w) << 16);
  *(uint2*)&CTXB[((size_t)(b * L_SEQ + i) * E_DIM) + h * HD + d0] = make_uint2(lo, hi);
}

// ---------------------------------------------------------------------------
// Workspace (24,379,392 B < proven 25.2 MB):
//   [0        .. 1572864)   Qw fp32
//   [1572864  .. 3145728)   Kw fp32
//   [3145728  .. 4718592)   Vw fp32
//   [4718592  .. 23592960)  CTXS fp32 (12 slabs)
//   [23592960 .. 24379392)  CTXB bf16 (reduced ctx, (b,l,e))
// ---------------------------------------------------------------------------
extern "C" void kernel_launch(void* const* d_in, const int* in_sizes, int n_in,
                              void* d_out, int out_size, void* d_ws, size_t ws_size,
                              hipStream_t stream)
{
  const float* x     = (const float*)d_in[0];
  const float* Wq    = (const float*)d_in[1];
  const float* Wk    = (const float*)d_in[2];
  const float* Wv    = (const float*)d_in[3];
  const float* Wo    = (const float*)d_in[4];
  const float* dde_w = (const float*)d_in[5];
  const float* dde_b = (const float*)d_in[6];
  float* out = (float*)d_out;

  char* ws = (char*)d_ws;
  float* Qw            = (float*)(ws + 0);
  float* Kw            = (float*)(ws + 1572864);
  float* Vw            = (float*)(ws + 3145728);
  float* CTXS          = (float*)(ws + 4718592);
  unsigned short* CTXB = (unsigned short*)(ws + 23592960);

  // 1) Q/K/V projections (fp32 in, convert-in-register, MFMA), head-scatter
  gemm_mfma<<<dim3(8, 12, 3), 256, 0, stream>>>(
      x, Wq, Wk, Wv, Qw, Kw, Vw, 2 * L_SEQ, E_DIM, E_DIM, 1, 0);

  // 2) fused pairwise core -> 12 fp32 slabs
  berry_main<<<dim3(JSPLIT, 12, NBH), 128, 0, stream>>>(
      Qw, Kw, Vw, dde_w, dde_b, CTXS);

  // 3) slab reduction + head transpose -> bf16
  ctx_reduce<<<384, 256, 0, stream>>>(CTXS, CTXB);

  // 4) output projection (A = bf16 ctx, Wo converted in-register)
  gemm_mfma<<<dim3(8, 12, 1), 256, 0, stream>>>(
      CTXB, Wo, nullptr, nullptr, out, nullptr, nullptr,
      2 * L_SEQ, E_DIM, E_DIM, 0, 1);
}

// Round 9
// 179.749 us; speedup vs baseline: 1.1716x; 1.1716x over previous
//
#include <hip/hip_runtime.h>
#include <math.h>

#define L_SEQ 384
#define E_DIM 512
#define NHEAD 8
#define NBH   16
#define HD    64
#define JSPLIT 12
#define JTILE  32          // L_SEQ / JSPLIT
#define PROJ_ELEMS (NBH * L_SEQ * HD)   // 393216
#define LOG2E 1.44269504f

typedef __attribute__((ext_vector_type(8))) __bf16 bf16x8;
typedef __attribute__((ext_vector_type(4))) float f32x4;

__device__ __forceinline__ float uniform_f(float v) {
  return __uint_as_float(__builtin_amdgcn_readfirstlane(__float_as_uint(v)));
}

__device__ __forceinline__ unsigned f2bf(float f) {   // RNE float->bf16 bits
  unsigned u = __float_as_uint(f);
  return (u + 0x7FFFu + ((u >> 16) & 1u)) >> 16;
}

__device__ __forceinline__ bf16x8 cvt8(float4 a, float4 b) {  // 8 fp32 -> bf16x8
  union { bf16x8 v; unsigned u[4]; } r;
  r.u[0] = f2bf(a.x) | (f2bf(a.y) << 16);
  r.u[1] = f2bf(a.z) | (f2bf(a.w) << 16);
  r.u[2] = f2bf(b.x) | (f2bf(b.y) << 16);
  r.u[3] = f2bf(b.z) | (f2bf(b.w) << 16);
  return r.v;
}

// ---------------------------------------------------------------------------
// Convert x|Wq|Wk|Wv (contiguous dst1) and Wo (dst2) to bf16 (R5-proven).
// ---------------------------------------------------------------------------
__global__ __launch_bounds__(256) void to_bf16_all(
    const float* __restrict__ x, const float* __restrict__ Wq,
    const float* __restrict__ Wk, const float* __restrict__ Wv,
    const float* __restrict__ Wo, unsigned short* __restrict__ dst1,
    unsigned short* __restrict__ dst2)
{
  int e0 = (blockIdx.x * 256 + threadIdx.x) * 4;
  if (e0 >= 1441792) return;
  const float* src; unsigned short* d; int s;
  if (e0 < 393216)       { src = x;  s = e0;           d = dst1 + e0; }
  else if (e0 < 655360)  { src = Wq; s = e0 - 393216;  d = dst1 + e0; }
  else if (e0 < 917504)  { src = Wk; s = e0 - 655360;  d = dst1 + e0; }
  else if (e0 < 1179648) { src = Wv; s = e0 - 917504;  d = dst1 + e0; }
  else                   { src = Wo; s = e0 - 1179648; d = dst2 + s;  }
  float4 v = *(const float4*)(src + s);
  unsigned lo = f2bf(v.x) | (f2bf(v.y) << 16);
  unsigned hi = f2bf(v.z) | (f2bf(v.w) << 16);
  *(uint2*)d = make_uint2(lo, hi);
}

// ---------------------------------------------------------------------------
// Pure-bf16 MFMA GEMM (R5-proven; R8 lesson: do NOT fold fp32->bf16 cvt in
// here — at ~1 block/CU it cost ~+40 us across the two GEMMs).
// C = A @ B^T. Block 256 = 4 waves; tile 64x64; wave = 16-row strip.
// mode 0: C[m*N+f]; mode 1: head-scatter C[((b*8+h)*L+l)*64+d].
// ---------------------------------------------------------------------------
__global__ __launch_bounds__(256) void gemm_mfma(
    const __bf16* __restrict__ A, const __bf16* __restrict__ B0,
    const __bf16* __restrict__ B1, const __bf16* __restrict__ B2,
    float* __restrict__ C0, float* __restrict__ C1, float* __restrict__ C2,
    int M, int N, int K, int mode)
{
  const int z = blockIdx.z;
  const __bf16* Bm = (z == 0) ? B0 : (z == 1) ? B1 : B2;
  float* Cp = (z == 0) ? C0 : (z == 1) ? C1 : C2;

  const int tid = threadIdx.x;
  const int wave = tid >> 6, lane = tid & 63;
  const int m0 = blockIdx.y * 64 + wave * 16;
  const int n0 = blockIdx.x * 64;
  const int mr = lane & 15, quad = lane >> 4;

  f32x4 acc[4];
  #pragma unroll
  for (int nt = 0; nt < 4; ++nt) acc[nt] = (f32x4){0.f, 0.f, 0.f, 0.f};

  const __bf16* ap = A + (size_t)(m0 + mr) * K + quad * 8;
  const __bf16* bp = Bm + (size_t)(n0 + mr) * K + quad * 8;

  #pragma unroll 4
  for (int k0 = 0; k0 < K; k0 += 32) {
    bf16x8 a = *(const bf16x8*)(ap + k0);
    #pragma unroll
    for (int nt = 0; nt < 4; ++nt) {
      bf16x8 b = *(const bf16x8*)(bp + (size_t)nt * 16 * K + k0);
      acc[nt] = __builtin_amdgcn_mfma_f32_16x16x32_bf16(a, b, acc[nt], 0, 0, 0);
    }
  }

  #pragma unroll
  for (int nt = 0; nt < 4; ++nt) {
    int n = n0 + nt * 16 + mr;
    #pragma unroll
    for (int r = 0; r < 4; ++r) {
      int m = m0 + quad * 4 + r;
      if (mode == 0) {
        Cp[(size_t)m * N + n] = acc[nt][r];
      } else {
        int b = m / L_SEQ, l = m % L_SEQ;
        int h = n >> 6, d = n & 63;
        Cp[((size_t)(b * NHEAD + h) * L_SEQ + l) * HD + d] = acc[nt][r];
      }
    }
  }
}

// ---------------------------------------------------------------------------
// Fused pairwise core v7.
// Gate algebra: T[i,j,p] = gb[p] + q_hat[i,:] . Ktilde_p[j,:]  (64-dim dot),
// Ktilde_p = sum_c (dde_w[p][c]/16) * P_c(k_hat), P_c = signed quaternion
// permutations. Phase 1 computes the whole 32x32x4 gate tile per block with
// 16 MFMAs/wave + sigmoid epilogue -> bf16 LDS. Phase 2 (jj loop) has NO
// cross-lane ops, NO transcendentals: ham + gate-apply + PV only.
// Block 128 = 32 i x 4 lanes, 4 atoms/thread; grid (12, 12, 16).
// ---------------------------------------------------------------------------
__global__ __launch_bounds__(128, 4) void berry_main(
    const float* __restrict__ Q, const float* __restrict__ K,
    const float* __restrict__ V, const float* __restrict__ dde_w,
    const float* __restrict__ dde_b, float* __restrict__ CTXS)
{
  __shared__ float kt[JTILE][HD];            // normalized k atoms (8 KB)
  __shared__ float vt[JTILE][HD];            // raw v (8 KB)
  __shared__ unsigned short gt[JTILE][32][4];// sigmoid gates bf16 [j][i][p] (8 KB)

  const int tid = threadIdx.x;
  const int bh = blockIdx.z;
  const int iy = blockIdx.y;
  const int ag = tid & 3;
  const int js = blockIdx.x;
  const int j0 = js * JTILE;

  const int wave = tid >> 6, lane = tid & 63;
  const int mr = lane & 15, quad = lane >> 4;
  const int p = mr & 3;                      // this lane's gate index in phase 1

  // per-lane gate weights w_c = dde_w[p*4+c]/16 and bias gb[p] (uniform loads
  // + 3-way selects, hoisted out of all loops)
  float w0, w1, w2, w3, gbp;
  {
    float s[16];
    #pragma unroll
    for (int t = 0; t < 16; ++t) s[t] = uniform_f(dde_w[t]) * 0.0625f;
    float b0 = uniform_f(dde_b[0]), b1 = uniform_f(dde_b[1]);
    float b2 = uniform_f(dde_b[2]), b3 = uniform_f(dde_b[3]);
    w0  = (p == 0) ? s[0]  : (p == 1) ? s[4]  : (p == 2) ? s[8]  : s[12];
    w1  = (p == 0) ? s[1]  : (p == 1) ? s[5]  : (p == 2) ? s[9]  : s[13];
    w2  = (p == 0) ? s[2]  : (p == 1) ? s[6]  : (p == 2) ? s[10] : s[14];
    w3  = (p == 0) ? s[3]  : (p == 1) ? s[7]  : (p == 2) ? s[11] : s[15];
    gbp = (p == 0) ? b0    : (p == 1) ? b1    : (p == 2) ? b2    : b3;
  }

  // stage K (normalized per atom) + V: 32 j x 16 atoms = 512, 4/thread
  #pragma unroll
  for (int pp = 0; pp < 4; ++pp) {
    int idx = tid + pp * 128;
    int jj = idx >> 4, at = idx & 15;
    size_t g = (size_t)(bh * L_SEQ + j0 + jj) * HD + at * 4;
    float4 kq = *(const float4*)(K + g);
    float d = kq.x * kq.x + kq.y * kq.y + kq.z * kq.z + kq.w * kq.w;
    float r = __builtin_amdgcn_rsqf(fmaxf(d, 1e-30f));
    kq.x *= r; kq.y *= r; kq.z *= r; kq.w *= r;
    *(float4*)&kt[jj][at * 4] = kq;
    *(float4*)&vt[jj][at * 4] = *(const float4*)(V + g);
  }
  __syncthreads();

  // ---- phase 1: T = q_hat @ Ktilde^T (MFMA), sigmoid -> gt ----
  {
    const int gi = iy * 32 + wave * 16 + mr;       // A-frag row (global i)
    f32x4 acc[8];
    #pragma unroll
    for (int nt = 0; nt < 8; ++nt) acc[nt] = (f32x4){0.f, 0.f, 0.f, 0.f};

    #pragma unroll
    for (int kk = 0; kk < 2; ++kk) {
      const int at0 = kk * 8 + quad * 2;           // 2 atoms of this k-slice
      // A-frag: q_hat atoms at0, at0+1
      const float* qp2 = Q + ((size_t)(bh * L_SEQ + gi) * HD + at0 * 4);
      float4 q0 = ((const float4*)qp2)[0];
      float4 q1 = ((const float4*)qp2)[1];
      float d0 = q0.x*q0.x + q0.y*q0.y + q0.z*q0.z + q0.w*q0.w;
      float d1 = q1.x*q1.x + q1.y*q1.y + q1.z*q1.z + q1.w*q1.w;
      float r0 = __builtin_amdgcn_rsqf(fmaxf(d0, 1e-30f));
      float r1 = __builtin_amdgcn_rsqf(fmaxf(d1, 1e-30f));
      q0.x *= r0; q0.y *= r0; q0.z *= r0; q0.w *= r0;
      q1.x *= r1; q1.y *= r1; q1.z *= r1; q1.w *= r1;
      bf16x8 afrag = cvt8(q0, q1);

      #pragma unroll
      for (int nt = 0; nt < 8; ++nt) {
        // B-frag row n = nt*16 + mr -> (jj = n>>2, p = mr&3); dims = 2 atoms
        const int jj = nt * 4 + (mr >> 2);
        float4 k0 = *(const float4*)&kt[jj][at0 * 4];
        float4 k1 = *(const float4*)&kt[jj][at0 * 4 + 4];
        float4 t0, t1;
        t0.x =  w0*k0.x + w1*k0.y + w2*k0.z + w3*k0.w;
        t0.y = -w0*k0.y + w1*k0.x - w2*k0.w + w3*k0.z;
        t0.z = -w0*k0.z + w1*k0.w + w2*k0.x - w3*k0.y;
        t0.w = -w0*k0.w - w1*k0.z + w2*k0.y + w3*k0.x;
        t1.x =  w0*k1.x + w1*k1.y + w2*k1.z + w3*k1.w;
        t1.y = -w0*k1.y + w1*k1.x - w2*k1.w + w3*k1.z;
        t1.z = -w0*k1.z + w1*k1.w + w2*k1.x - w3*k1.y;
        t1.w = -w0*k1.w - w1*k1.z + w2*k1.y + w3*k1.x;
        bf16x8 bfrag = cvt8(t0, t1);
        acc[nt] = __builtin_amdgcn_mfma_f32_16x16x32_bf16(afrag, bfrag, acc[nt], 0, 0, 0);
      }
    }

    // epilogue: C layout row = quad*4+r (i), col = mr (n); sigmoid; store bf16
    #pragma unroll
    for (int nt = 0; nt < 8; ++nt) {
      const int jj = nt * 4 + (mr >> 2);
      #pragma unroll
      for (int r = 0; r < 4; ++r) {
        const int il = wave * 16 + quad * 4 + r;
        float t = acc[nt][r] + gbp;
        float g = __builtin_amdgcn_rcpf(1.f + __builtin_amdgcn_exp2f(t * -LOG2E));
        gt[jj][il][p] = (unsigned short)f2bf(g);
      }
    }
  }
  __syncthreads();

  // ---- phase 2: ham + gate-apply + PV (no cross-lane, no transcendentals) --
  const int i = iy * 32 + (tid >> 2);
  float4 qa[4], ctx[4];
  const float* qp = Q + ((size_t)(bh * L_SEQ + i) * HD + ag * 16);
  #pragma unroll
  for (int t = 0; t < 4; ++t) {
    float4 q = ((const float4*)qp)[t];
    float d = q.x * q.x + q.y * q.y + q.z * q.z + q.w * q.w;
    float r = __builtin_amdgcn_rsqf(fmaxf(d, 1e-30f));
    qa[t].x = q.x * r; qa[t].y = q.y * r; qa[t].z = q.z * r; qa[t].w = q.w * r;
    ctx[t] = make_float4(0.f, 0.f, 0.f, 0.f);
  }

  #pragma unroll 2
  for (int jj = 0; jj < JTILE; ++jj) {
    uint2 gu = *(const uint2*)&gt[jj][tid >> 2][0];
    float gx = __uint_as_float(gu.x << 16);
    float gy = __uint_as_float(gu.x & 0xffff0000u);
    float gz = __uint_as_float(gu.y << 16);
    float gw_ = __uint_as_float(gu.y & 0xffff0000u);

    #pragma unroll
    for (int a = 0; a < 4; ++a) {
      float4 kq = *(const float4*)&kt[jj][ag * 16 + a * 4];
      float hx = qa[a].x * kq.x - qa[a].y * kq.y - qa[a].z * kq.z - qa[a].w * kq.w;
      float hy = qa[a].x * kq.y + qa[a].y * kq.x + qa[a].z * kq.w - qa[a].w * kq.z;
      float hz = qa[a].x * kq.z - qa[a].y * kq.w + qa[a].z * kq.x + qa[a].w * kq.y;
      float hw = qa[a].x * kq.w + qa[a].y * kq.z - qa[a].z * kq.y + qa[a].w * kq.x;
      float4 vq = *(const float4*)&vt[jj][ag * 16 + a * 4];
      float sx = hx * gx, sy = hy * gy, sz = hz * gz, sw = hw * gw_;
      ctx[a].x += sx * vq.x - sy * vq.y - sz * vq.z - sw * vq.w;
      ctx[a].y += sx * vq.y + sy * vq.x + sz * vq.w - sw * vq.z;
      ctx[a].z += sx * vq.z - sy * vq.w + sz * vq.x + sw * vq.y;
      ctx[a].w += sx * vq.w + sy * vq.z - sz * vq.y + sw * vq.x;
    }
  }

  // plain stores into this j-chunk's slab
  float* cp = CTXS + ((size_t)(js * NBH + bh) * L_SEQ + i) * HD + ag * 16;
  #pragma unroll
  for (int t = 0; t < 4; ++t) ((float4*)cp)[t] = ctx[t];
}

// ---------------------------------------------------------------------------
// Sum the JSPLIT ctx slabs, transpose heads into (b,l,e), emit bf16 (R5).
// ---------------------------------------------------------------------------
__global__ __launch_bounds__(256) void ctx_reduce(
    const float* __restrict__ CTXS, unsigned short* __restrict__ CTXB)
{
  int idx = blockIdx.x * 256 + threadIdx.x;      // over 98304 float4 groups
  int row = idx >> 4;                            // bh*L + i
  int d0 = (idx & 15) * 4;
  float4 s = make_float4(0.f, 0.f, 0.f, 0.f);
  #pragma unroll
  for (int js = 0; js < JSPLIT; ++js) {
    float4 v = *(const float4*)&CTXS[(size_t)js * PROJ_ELEMS + (size_t)row * HD + d0];
    s.x += v.x; s.y += v.y; s.z += v.z; s.w += v.w;
  }
  int bh = row / L_SEQ, i = row - bh * L_SEQ;
  int b = bh >> 3, h = bh & 7;
  unsigned lo = f2bf(s.x) | (f2bf(s.y) << 16);
  unsigned hi = f2bf(s.z) | (f2bf(s.w) << 16);
  *(uint2*)&CTXB[((size_t)(b * L_SEQ + i) * E_DIM) + h * HD + d0] = make_uint2(lo, hi);
}

// ---------------------------------------------------------------------------
// Workspace (R5-proven layout, 24,379,392 B):
//   [0          .. 1572864)  Qw fp32            | CTXB bf16 (after berry)
//   [1572864    .. 3145728)  Kw fp32
//   [3145728    .. 4718592)  Vw fp32
//   [4718592    .. 23592960) CTXS (12 slabs)    | xb|Wqb|Wkb|Wvb bf16 (pre-berry)
//   [23592960   .. 24117248) Wob bf16
// ---------------------------------------------------------------------------
extern "C" void kernel_launch(void* const* d_in, const int* in_sizes, int n_in,
                              void* d_out, int out_size, void* d_ws, size_t ws_size,
                              hipStream_t stream)
{
  const float* x     = (const float*)d_in[0];
  const float* Wq    = (const float*)d_in[1];
  const float* Wk    = (const float*)d_in[2];
  const float* Wv    = (const float*)d_in[3];
  const float* Wo    = (const float*)d_in[4];
  const float* dde_w = (const float*)d_in[5];
  const float* dde_b = (const float*)d_in[6];
  float* out = (float*)d_out;

  char* ws = (char*)d_ws;
  float* Qw   = (float*)(ws + 0);
  float* Kw   = (float*)(ws + 1572864);
  float* Vw   = (float*)(ws + 3145728);
  float* CTXS = (float*)(ws + 4718592);
  unsigned short* xb   = (unsigned short*)(ws + 4718592);   // dead before berry
  unsigned short* Wqb  = (unsigned short*)(ws + 5505024);
  unsigned short* Wkb  = (unsigned short*)(ws + 6029312);
  unsigned short* Wvb  = (unsigned short*)(ws + 6553600);
  unsigned short* Wob  = (unsigned short*)(ws + 23592960);
  unsigned short* CTXB = (unsigned short*)(ws + 0);         // born after Qw dead

  // 1) fp32 -> bf16 conversions
  to_bf16_all<<<1408, 256, 0, stream>>>(x, Wq, Wk, Wv, Wo, xb, Wob);

  // 2) Q/K/V projections: pure-bf16 MFMA, head-scatter fp32 epilogue
  gemm_mfma<<<dim3(8, 12, 3), 256, 0, stream>>>(
      (const __bf16*)xb, (const __bf16*)Wqb, (const __bf16*)Wkb, (const __bf16*)Wvb,
      Qw, Kw, Vw, 2 * L_SEQ, E_DIM, E_DIM, 1);

  // 3) fused pairwise core (MFMA gate phase + VALU PV phase)
  berry_main<<<dim3(JSPLIT, 12, NBH), 128, 0, stream>>>(
      Qw, Kw, Vw, dde_w, dde_b, CTXS);

  // 4) slab reduction + head transpose -> bf16
  ctx_reduce<<<384, 256, 0, stream>>>(CTXS, CTXB);

  // 5) output projection: pure-bf16 MFMA, fp32 out
  gemm_mfma<<<dim3(8, 12, 1), 256, 0, stream>>>(
      (const __bf16*)CTXB, (const __bf16*)Wob, nullptr, nullptr,
      out, nullptr, nullptr, 2 * L_SEQ, E_DIM, E_DIM, 0);
}

// Round 10
// 176.897 us; speedup vs baseline: 1.1905x; 1.0161x over previous
//
#include <hip/hip_runtime.h>
#include <math.h>

#define L_SEQ 384
#define E_DIM 512
#define NHEAD 8
#define NBH   16
#define HD    64
#define JSPLIT 12
#define JTILE  32          // L_SEQ / JSPLIT
#define PROJ_ELEMS (NBH * L_SEQ * HD)   // 393216

typedef __attribute__((ext_vector_type(8))) __bf16 bf16x8;
typedef __attribute__((ext_vector_type(4))) float f32x4;

__device__ __forceinline__ float uniform_f(float v) {
  return __uint_as_float(__builtin_amdgcn_readfirstlane(__float_as_uint(v)));
}

__device__ __forceinline__ unsigned f2bf(float f) {   // RNE float->bf16 bits
  unsigned u = __float_as_uint(f);
  return (u + 0x7FFFu + ((u >> 16) & 1u)) >> 16;
}

// sum over the 4 lanes of each quad — pure-VALU DPP quad_perm butterfly
__device__ __forceinline__ float quad_sum(float x) {
  x += __int_as_float(__builtin_amdgcn_mov_dpp(__float_as_int(x), 0xB1, 0xF, 0xF, 0)); // xor 1
  x += __int_as_float(__builtin_amdgcn_mov_dpp(__float_as_int(x), 0x4E, 0xF, 0xF, 0)); // xor 2
  return x;
}

// ---------------------------------------------------------------------------
// Convert x|Wq|Wk|Wv (contiguous dst1) and Wo (dst2) to bf16 (R5-proven;
// keeping this as its own node is net-positive: pure-bf16 GEMMs are ~15 us
// cheaper than cvt-in-GEMM at ~1 block/CU — R8 lesson).
// ---------------------------------------------------------------------------
__global__ __launch_bounds__(256) void to_bf16_all(
    const float* __restrict__ x, const float* __restrict__ Wq,
    const float* __restrict__ Wk, const float* __restrict__ Wv,
    const float* __restrict__ Wo, unsigned short* __restrict__ dst1,
    unsigned short* __restrict__ dst2)
{
  int e0 = (blockIdx.x * 256 + threadIdx.x) * 4;
  if (e0 >= 1441792) return;
  const float* src; unsigned short* d; int s;
  if (e0 < 393216)       { src = x;  s = e0;           d = dst1 + e0; }
  else if (e0 < 655360)  { src = Wq; s = e0 - 393216;  d = dst1 + e0; }
  else if (e0 < 917504)  { src = Wk; s = e0 - 655360;  d = dst1 + e0; }
  else if (e0 < 1179648) { src = Wv; s = e0 - 917504;  d = dst1 + e0; }
  else                   { src = Wo; s = e0 - 1179648; d = dst2 + s;  }
  float4 v = *(const float4*)(src + s);
  unsigned lo = f2bf(v.x) | (f2bf(v.y) << 16);
  unsigned hi = f2bf(v.z) | (f2bf(v.w) << 16);
  *(uint2*)d = make_uint2(lo, hi);
}

// ---------------------------------------------------------------------------
// Pure-bf16 MFMA GEMM (R5-proven). C = A @ B^T.
// Block 256 = 4 waves; tile 64x64; wave = 16-row strip, 4 n-tiles.
// mode 0: C[m*N+f]; mode 1: head-scatter C[((b*8+h)*L+l)*64+d].
// ---------------------------------------------------------------------------
__global__ __launch_bounds__(256) void gemm_mfma(
    const __bf16* __restrict__ A, const __bf16* __restrict__ B0,
    const __bf16* __restrict__ B1, const __bf16* __restrict__ B2,
    float* __restrict__ C0, float* __restrict__ C1, float* __restrict__ C2,
    int M, int N, int K, int mode)
{
  const int z = blockIdx.z;
  const __bf16* Bm = (z == 0) ? B0 : (z == 1) ? B1 : B2;
  float* Cp = (z == 0) ? C0 : (z == 1) ? C1 : C2;

  const int tid = threadIdx.x;
  const int wave = tid >> 6, lane = tid & 63;
  const int m0 = blockIdx.y * 64 + wave * 16;
  const int n0 = blockIdx.x * 64;
  const int mr = lane & 15, quad = lane >> 4;

  f32x4 acc[4];
  #pragma unroll
  for (int nt = 0; nt < 4; ++nt) acc[nt] = (f32x4){0.f, 0.f, 0.f, 0.f};

  const __bf16* ap = A + (size_t)(m0 + mr) * K + quad * 8;
  const __bf16* bp = Bm + (size_t)(n0 + mr) * K + quad * 8;

  #pragma unroll 4
  for (int k0 = 0; k0 < K; k0 += 32) {
    bf16x8 a = *(const bf16x8*)(ap + k0);
    #pragma unroll
    for (int nt = 0; nt < 4; ++nt) {
      bf16x8 b = *(const bf16x8*)(bp + (size_t)nt * 16 * K + k0);
      acc[nt] = __builtin_amdgcn_mfma_f32_16x16x32_bf16(a, b, acc[nt], 0, 0, 0);
    }
  }

  #pragma unroll
  for (int nt = 0; nt < 4; ++nt) {
    int n = n0 + nt * 16 + mr;
    #pragma unroll
    for (int r = 0; r < 4; ++r) {
      int m = m0 + quad * 4 + r;
      if (mode == 0) {
        Cp[(size_t)m * N + n] = acc[nt][r];
      } else {
        int b = m / L_SEQ, l = m % L_SEQ;
        int h = n >> 6, d = n & 63;
        Cp[((size_t)(b * NHEAD + h) * L_SEQ + l) * HD + d] = acc[nt][r];
      }
    }
  }
}

// ---------------------------------------------------------------------------
// Fused pairwise core (round-5 proven body; R9's MFMA-gate variant was
// neutral + added LDS conflicts, reverted).
// ONLY change vs R5: __launch_bounds__(128, 8) — R5 ran at 8 waves/CU
// (Occupancy 25%) with VALUBusy 65%; VGPR=64 and LDS 16.4 KB permit ~18
// waves/CU, and the declared 4 waves/EU looked like the residency cap.
// VGPR cap at 8/EU is 64 = R5's natural allocation -> no spill expected.
// Block 128 = 32 i x 4 lanes, 4 atoms/thread; grid (12, 12, 16).
// ---------------------------------------------------------------------------
__global__ __launch_bounds__(128, 8) void berry_main(
    const float* __restrict__ Q, const float* __restrict__ K,
    const float* __restrict__ V, const float* __restrict__ dde_w,
    const float* __restrict__ dde_b, float* __restrict__ CTXS)
{
  __shared__ float kt[JTILE][HD];   // normalized k atoms
  __shared__ float vt[JTILE][HD];   // raw v

  const int tid = threadIdx.x;
  const int bh = blockIdx.z;
  const int i = blockIdx.y * 32 + (tid >> 2);
  const int ag = tid & 3;                 // lane-in-quad: atoms ag*4 .. ag*4+3
  const int js = blockIdx.x;
  const int j0 = js * JTILE;

  // gate params in SGPRs; mean over 16 atoms folded into weights
  float gw[16];
  #pragma unroll
  for (int t = 0; t < 16; ++t) gw[t] = uniform_f(dde_w[t]) * 0.0625f;
  const float gb0 = uniform_f(dde_b[0]), gb1 = uniform_f(dde_b[1]);
  const float gb2 = uniform_f(dde_b[2]), gb3 = uniform_f(dde_b[3]);

  float4 qa[4], ctx[4];
  const float* qp = Q + ((size_t)(bh * L_SEQ + i) * HD + ag * 16);
  #pragma unroll
  for (int t = 0; t < 4; ++t) {
    float4 q = ((const float4*)qp)[t];
    float d = q.x * q.x + q.y * q.y + q.z * q.z + q.w * q.w;
    float r = __builtin_amdgcn_rsqf(fmaxf(d, 1e-30f));
    qa[t].x = q.x * r; qa[t].y = q.y * r; qa[t].z = q.z * r; qa[t].w = q.w * r;
    ctx[t] = make_float4(0.f, 0.f, 0.f, 0.f);
  }

  // stage K (normalized per atom: |ham(q,k)| = |q||k|) + V
  #pragma unroll
  for (int p = 0; p < 4; ++p) {
    int idx = tid + p * 128;
    int jj = idx >> 4, at = idx & 15;
    size_t g = (size_t)(bh * L_SEQ + j0 + jj) * HD + at * 4;
    float4 kq = *(const float4*)(K + g);
    float d = kq.x * kq.x + kq.y * kq.y + kq.z * kq.z + kq.w * kq.w;
    float r = __builtin_amdgcn_rsqf(fmaxf(d, 1e-30f));
    kq.x *= r; kq.y *= r; kq.z *= r; kq.w *= r;
    *(float4*)&kt[jj][at * 4] = kq;
    *(float4*)&vt[jj][at * 4] = *(const float4*)(V + g);
  }
  __syncthreads();

  for (int jj = 0; jj < JTILE; ++jj) {
    float4 h[4];
    float gsx = 0.f, gsy = 0.f, gsz = 0.f, gsw = 0.f;
    #pragma unroll
    for (int a = 0; a < 4; ++a) {
      float4 kq = *(const float4*)&kt[jj][ag * 16 + a * 4];
      h[a].x = qa[a].x * kq.x - qa[a].y * kq.y - qa[a].z * kq.z - qa[a].w * kq.w;
      h[a].y = qa[a].x * kq.y + qa[a].y * kq.x + qa[a].z * kq.w - qa[a].w * kq.z;
      h[a].z = qa[a].x * kq.z - qa[a].y * kq.w + qa[a].z * kq.x + qa[a].w * kq.y;
      h[a].w = qa[a].x * kq.w + qa[a].y * kq.z - qa[a].z * kq.y + qa[a].w * kq.x;
      gsx += h[a].x; gsy += h[a].y; gsz += h[a].z; gsw += h[a].w;
    }
    gsx = quad_sum(gsx); gsy = quad_sum(gsy);
    gsz = quad_sum(gsz); gsw = quad_sum(gsw);

    float t0 = gb0 + gw[0]  * gsx + gw[1]  * gsy + gw[2]  * gsz + gw[3]  * gsw;
    float t1 = gb1 + gw[4]  * gsx + gw[5]  * gsy + gw[6]  * gsz + gw[7]  * gsw;
    float t2 = gb2 + gw[8]  * gsx + gw[9]  * gsy + gw[10] * gsz + gw[11] * gsw;
    float t3 = gb3 + gw[12] * gsx + gw[13] * gsy + gw[14] * gsz + gw[15] * gsw;
    float4 g;
    g.x = __builtin_amdgcn_rcpf(1.f + __expf(-t0));
    g.y = __builtin_amdgcn_rcpf(1.f + __expf(-t1));
    g.z = __builtin_amdgcn_rcpf(1.f + __expf(-t2));
    g.w = __builtin_amdgcn_rcpf(1.f + __expf(-t3));

    #pragma unroll
    for (int a = 0; a < 4; ++a) {
      float4 vq = *(const float4*)&vt[jj][ag * 16 + a * 4];
      float sx = h[a].x * g.x, sy = h[a].y * g.y;
      float sz = h[a].z * g.z, sw = h[a].w * g.w;
      ctx[a].x += sx * vq.x - sy * vq.y - sz * vq.z - sw * vq.w;
      ctx[a].y += sx * vq.y + sy * vq.x + sz * vq.w - sw * vq.z;
      ctx[a].z += sx * vq.z - sy * vq.w + sz * vq.x + sw * vq.y;
      ctx[a].w += sx * vq.w + sy * vq.z - sz * vq.y + sw * vq.x;
    }
  }

  // plain stores into this j-chunk's slab
  float* cp = CTXS + ((size_t)(js * NBH + bh) * L_SEQ + i) * HD + ag * 16;
  #pragma unroll
  for (int t = 0; t < 4; ++t) ((float4*)cp)[t] = ctx[t];
}

// ---------------------------------------------------------------------------
// Sum the JSPLIT ctx slabs, transpose heads into (b,l,e), emit bf16 (R5).
// ---------------------------------------------------------------------------
__global__ __launch_bounds__(256) void ctx_reduce(
    const float* __restrict__ CTXS, unsigned short* __restrict__ CTXB)
{
  int idx = blockIdx.x * 256 + threadIdx.x;      // over 98304 float4 groups
  int row = idx >> 4;                            // bh*L + i
  int d0 = (idx & 15) * 4;
  float4 s = make_float4(0.f, 0.f, 0.f, 0.f);
  #pragma unroll
  for (int js = 0; js < JSPLIT; ++js) {
    float4 v = *(const float4*)&CTXS[(size_t)js * PROJ_ELEMS + (size_t)row * HD + d0];
    s.x += v.x; s.y += v.y; s.z += v.z; s.w += v.w;
  }
  int bh = row / L_SEQ, i = row - bh * L_SEQ;
  int b = bh >> 3, h = bh & 7;
  unsigned lo = f2bf(s.x) | (f2bf(s.y) << 16);
  unsigned hi = f2bf(s.z) | (f2bf(s.w) << 16);
  *(uint2*)&CTXB[((size_t)(b * L_SEQ + i) * E_DIM) + h * HD + d0] = make_uint2(lo, hi);
}

// ---------------------------------------------------------------------------
// Workspace (R5-proven layout, 24,379,392 B):
//   [0          .. 1572864)  Qw fp32            | CTXB bf16 (after berry)
//   [1572864    .. 3145728)  Kw fp32
//   [3145728    .. 4718592)  Vw fp32
//   [4718592    .. 23592960) CTXS (12 slabs)    | xb|Wqb|Wkb|Wvb bf16 (pre-berry)
//   [23592960   .. 24117248) Wob bf16
// ---------------------------------------------------------------------------
extern "C" void kernel_launch(void* const* d_in, const int* in_sizes, int n_in,
                              void* d_out, int out_size, void* d_ws, size_t ws_size,
                              hipStream_t stream)
{
  const float* x     = (const float*)d_in[0];
  const float* Wq    = (const float*)d_in[1];
  const float* Wk    = (const float*)d_in[2];
  const float* Wv    = (const float*)d_in[3];
  const float* Wo    = (const float*)d_in[4];
  const float* dde_w = (const float*)d_in[5];
  const float* dde_b = (const float*)d_in[6];
  float* out = (float*)d_out;

  char* ws = (char*)d_ws;
  float* Qw   = (float*)(ws + 0);
  float* Kw   = (float*)(ws + 1572864);
  float* Vw   = (float*)(ws + 3145728);
  float* CTXS = (float*)(ws + 4718592);
  unsigned short* xb   = (unsigned short*)(ws + 4718592);   // dead before berry
  unsigned short* Wqb  = (unsigned short*)(ws + 5505024);
  unsigned short* Wkb  = (unsigned short*)(ws + 6029312);
  unsigned short* Wvb  = (unsigned short*)(ws + 6553600);
  unsigned short* Wob  = (unsigned short*)(ws + 23592960);
  unsigned short* CTXB = (unsigned short*)(ws + 0);         // born after Qw dead

  // 1) fp32 -> bf16 conversions
  to_bf16_all<<<1408, 256, 0, stream>>>(x, Wq, Wk, Wv, Wo, xb, Wob);

  // 2) Q/K/V projections: pure-bf16 MFMA, head-scatter fp32 epilogue
  gemm_mfma<<<dim3(8, 12, 3), 256, 0, stream>>>(
      (const __bf16*)xb, (const __bf16*)Wqb, (const __bf16*)Wkb, (const __bf16*)Wvb,
      Qw, Kw, Vw, 2 * L_SEQ, E_DIM, E_DIM, 1);

  // 3) fused pairwise core -> 12 fp32 slabs
  berry_main<<<dim3(JSPLIT, 12, NBH), 128, 0, stream>>>(
      Qw, Kw, Vw, dde_w, dde_b, CTXS);

  // 4) slab reduction + head transpose -> bf16
  ctx_reduce<<<384, 256, 0, stream>>>(CTXS, CTXB);

  // 5) output projection: pure-bf16 MFMA, fp32 out
  gemm_mfma<<<dim3(8, 12, 1), 256, 0, stream>>>(
      (const __bf16*)CTXB, (const __bf16*)Wob, nullptr, nullptr,
      out, nullptr, nullptr, 2 * L_SEQ, E_DIM, E_DIM, 0);
}

// Round 11
// 164.973 us; speedup vs baseline: 1.2765x; 1.0723x over previous
//
#include <hip/hip_runtime.h>
#include <math.h>

#define L_SEQ 384
#define E_DIM 512
#define NHEAD 8
#define NBH   16
#define HD    64
#define JSPLIT 12
#define JTILE  32          // L_SEQ / JSPLIT
#define PROJ_ELEMS (NBH * L_SEQ * HD)   // 393216
#define LOG2E 1.44269504f

typedef __attribute__((ext_vector_type(8))) __bf16 bf16x8;
typedef __attribute__((ext_vector_type(4))) float f32x4;
typedef __attribute__((ext_vector_type(2))) float f32x2;

__device__ __forceinline__ float uniform_f(float v) {
  return __uint_as_float(__builtin_amdgcn_readfirstlane(__float_as_uint(v)));
}

__device__ __forceinline__ unsigned f2bf(float f) {   // RNE float->bf16 bits
  unsigned u = __float_as_uint(f);
  return (u + 0x7FFFu + ((u >> 16) & 1u)) >> 16;
}

// quad_perm DPP helpers (pure VALU, no LDS pipe)
__device__ __forceinline__ float quad_sum(float x) {
  x += __int_as_float(__builtin_amdgcn_mov_dpp(__float_as_int(x), 0xB1, 0xF, 0xF, 0)); // xor 1
  x += __int_as_float(__builtin_amdgcn_mov_dpp(__float_as_int(x), 0x4E, 0xF, 0xF, 0)); // xor 2
  return x;
}
template <int PAT>
__device__ __forceinline__ float quad_bcast(float x) {
  return __int_as_float(__builtin_amdgcn_mov_dpp(__float_as_int(x), PAT, 0xF, 0xF, 0));
}

// ---------------------------------------------------------------------------
// Convert x|Wq|Wk|Wv (contiguous dst1) and Wo (dst2) to bf16 (R5-proven).
// ---------------------------------------------------------------------------
__global__ __launch_bounds__(256) void to_bf16_all(
    const float* __restrict__ x, const float* __restrict__ Wq,
    const float* __restrict__ Wk, const float* __restrict__ Wv,
    const float* __restrict__ Wo, unsigned short* __restrict__ dst1,
    unsigned short* __restrict__ dst2)
{
  int e0 = (blockIdx.x * 256 + threadIdx.x) * 4;
  if (e0 >= 1441792) return;
  const float* src; unsigned short* d; int s;
  if (e0 < 393216)       { src = x;  s = e0;           d = dst1 + e0; }
  else if (e0 < 655360)  { src = Wq; s = e0 - 393216;  d = dst1 + e0; }
  else if (e0 < 917504)  { src = Wk; s = e0 - 655360;  d = dst1 + e0; }
  else if (e0 < 1179648) { src = Wv; s = e0 - 917504;  d = dst1 + e0; }
  else                   { src = Wo; s = e0 - 1179648; d = dst2 + s;  }
  float4 v = *(const float4*)(src + s);
  unsigned lo = f2bf(v.x) | (f2bf(v.y) << 16);
  unsigned hi = f2bf(v.z) | (f2bf(v.w) << 16);
  *(uint2*)d = make_uint2(lo, hi);
}

// ---------------------------------------------------------------------------
// Pure-bf16 MFMA GEMM (R5-proven). C = A @ B^T.
// Block 256 = 4 waves; tile 64x64; wave = 16-row strip, 4 n-tiles.
// mode 0: C[m*N+f]; mode 1: head-scatter C[((b*8+h)*L+l)*64+d].
// ---------------------------------------------------------------------------
__global__ __launch_bounds__(256) void gemm_mfma(
    const __bf16* __restrict__ A, const __bf16* __restrict__ B0,
    const __bf16* __restrict__ B1, const __bf16* __restrict__ B2,
    float* __restrict__ C0, float* __restrict__ C1, float* __restrict__ C2,
    int M, int N, int K, int mode)
{
  const int z = blockIdx.z;
  const __bf16* Bm = (z == 0) ? B0 : (z == 1) ? B1 : B2;
  float* Cp = (z == 0) ? C0 : (z == 1) ? C1 : C2;

  const int tid = threadIdx.x;
  const int wave = tid >> 6, lane = tid & 63;
  const int m0 = blockIdx.y * 64 + wave * 16;
  const int n0 = blockIdx.x * 64;
  const int mr = lane & 15, quad = lane >> 4;

  f32x4 acc[4];
  #pragma unroll
  for (int nt = 0; nt < 4; ++nt) acc[nt] = (f32x4){0.f, 0.f, 0.f, 0.f};

  const __bf16* ap = A + (size_t)(m0 + mr) * K + quad * 8;
  const __bf16* bp = Bm + (size_t)(n0 + mr) * K + quad * 8;

  #pragma unroll 4
  for (int k0 = 0; k0 < K; k0 += 32) {
    bf16x8 a = *(const bf16x8*)(ap + k0);
    #pragma unroll
    for (int nt = 0; nt < 4; ++nt) {
      bf16x8 b = *(const bf16x8*)(bp + (size_t)nt * 16 * K + k0);
      acc[nt] = __builtin_amdgcn_mfma_f32_16x16x32_bf16(a, b, acc[nt], 0, 0, 0);
    }
  }

  #pragma unroll
  for (int nt = 0; nt < 4; ++nt) {
    int n = n0 + nt * 16 + mr;
    #pragma unroll
    for (int r = 0; r < 4; ++r) {
      int m = m0 + quad * 4 + r;
      if (mode == 0) {
        Cp[(size_t)m * N + n] = acc[nt][r];
      } else {
        int b = m / L_SEQ, l = m % L_SEQ;
        int h = n >> 6, d = n & 63;
        Cp[((size_t)(b * NHEAD + h) * L_SEQ + l) * HD + d] = acc[nt][r];
      }
    }
  }
}

// ---------------------------------------------------------------------------
// Fused pairwise core v8 = R5 structure + packed-fp32 math + gate dedup.
//  * Hamilton/PV as f32x2 arithmetic -> v_pk_fma_f32 (dual-pipe fp32).
//  * Gate: 4-comp quad_sum, then each lane computes ONLY its own p
//    (weights selected by ag, pre-scaled by -LOG2E/16), sigmoid once,
//    4 DPP quad-broadcasts share g0..g3. Was: 16 FMA + 8 transcendentals
//    per lane, all 4 lanes redundant.
// Block 128 = 32 i x 4 lanes, 4 atoms/thread; grid (12, 12, 16).
// (128,4): occupancy is LDS-pinned at ~4 blocks/CU (R10); give the
// allocator headroom instead of a cap it can't honor.
// ---------------------------------------------------------------------------
__global__ __launch_bounds__(128, 4) void berry_main(
    const float* __restrict__ Q, const float* __restrict__ K,
    const float* __restrict__ V, const float* __restrict__ dde_w,
    const float* __restrict__ dde_b, float* __restrict__ CTXS)
{
  __shared__ float kt[JTILE][HD];   // normalized k atoms
  __shared__ float vt[JTILE][HD];   // raw v

  const int tid = threadIdx.x;
  const int bh = blockIdx.z;
  const int i = blockIdx.y * 32 + (tid >> 2);
  const int ag = tid & 3;                 // lane-in-quad: atoms ag*4 .. ag*4+3
  const int js = blockIdx.x;
  const int j0 = js * JTILE;

  // this lane's gate row p = ag: weights * (-LOG2E/16), bias * (-LOG2E)
  float w0, w1, w2, w3, gbp;
  {
    float s[16];
    #pragma unroll
    for (int t = 0; t < 16; ++t) s[t] = uniform_f(dde_w[t]) * (-LOG2E * 0.0625f);
    float b0 = uniform_f(dde_b[0]) * -LOG2E, b1 = uniform_f(dde_b[1]) * -LOG2E;
    float b2 = uniform_f(dde_b[2]) * -LOG2E, b3 = uniform_f(dde_b[3]) * -LOG2E;
    w0  = (ag == 0) ? s[0]  : (ag == 1) ? s[4]  : (ag == 2) ? s[8]  : s[12];
    w1  = (ag == 0) ? s[1]  : (ag == 1) ? s[5]  : (ag == 2) ? s[9]  : s[13];
    w2  = (ag == 0) ? s[2]  : (ag == 1) ? s[6]  : (ag == 2) ? s[10] : s[14];
    w3  = (ag == 0) ? s[3]  : (ag == 1) ? s[7]  : (ag == 2) ? s[11] : s[15];
    gbp = (ag == 0) ? b0    : (ag == 1) ? b1    : (ag == 2) ? b2    : b3;
  }

  float4 qa[4];
  f32x2 c01[4], c23[4];
  const float* qp = Q + ((size_t)(bh * L_SEQ + i) * HD + ag * 16);
  #pragma unroll
  for (int t = 0; t < 4; ++t) {
    float4 q = ((const float4*)qp)[t];
    float d = q.x * q.x + q.y * q.y + q.z * q.z + q.w * q.w;
    float r = __builtin_amdgcn_rsqf(fmaxf(d, 1e-30f));
    qa[t].x = q.x * r; qa[t].y = q.y * r; qa[t].z = q.z * r; qa[t].w = q.w * r;
    c01[t] = (f32x2){0.f, 0.f};
    c23[t] = (f32x2){0.f, 0.f};
  }

  // stage K (normalized per atom: |ham(q,k)| = |q||k|) + V
  #pragma unroll
  for (int p = 0; p < 4; ++p) {
    int idx = tid + p * 128;
    int jj = idx >> 4, at = idx & 15;
    size_t g = (size_t)(bh * L_SEQ + j0 + jj) * HD + at * 4;
    float4 kq = *(const float4*)(K + g);
    float d = kq.x * kq.x + kq.y * kq.y + kq.z * kq.z + kq.w * kq.w;
    float r = __builtin_amdgcn_rsqf(fmaxf(d, 1e-30f));
    kq.x *= r; kq.y *= r; kq.z *= r; kq.w *= r;
    *(float4*)&kt[jj][at * 4] = kq;
    *(float4*)&vt[jj][at * 4] = *(const float4*)(V + g);
  }
  __syncthreads();

  for (int jj = 0; jj < JTILE; ++jj) {
    f32x2 h01[4], h23[4];
    f32x2 gs01 = (f32x2){0.f, 0.f}, gs23 = (f32x2){0.f, 0.f};

    #pragma unroll
    for (int a = 0; a < 4; ++a) {
      float4 kq = *(const float4*)&kt[jj][ag * 16 + a * 4];
      f32x2 k01 = (f32x2){kq.x, kq.y}, k23 = (f32x2){kq.z, kq.w};
      f32x2 s01 = (f32x2){kq.y, kq.x}, s23 = (f32x2){kq.w, kq.z};
      f32x2 qx2 = (f32x2){qa[a].x, qa[a].x};
      f32x2 qy2 = (f32x2){qa[a].y, qa[a].y};
      f32x2 qz2 = (f32x2){qa[a].z, qa[a].z};
      f32x2 qw2 = (f32x2){qa[a].w, qa[a].w};
      // h01 = qx*(kx,ky) + qy*(-ky,kx) + qz*(-kz,kw) + qw*(-kw,-kz)
      f32x2 t = qx2 * k01;
      t += qy2 * (f32x2){-s01.x, s01.y};
      t += qz2 * (f32x2){-k23.x, k23.y};
      t += qw2 * (f32x2){-s23.x, -s23.y};
      h01[a] = t;
      // h23 = qx*(kz,kw) + qy*(-kw,kz) + qz*(kx,-ky) + qw*(ky,kx)
      f32x2 u = qx2 * k23;
      u += qy2 * (f32x2){-s23.x, s23.y};
      u += qz2 * (f32x2){k01.x, -k01.y};
      u += qw2 * s01;
      h23[a] = u;
      gs01 += t; gs23 += u;
    }

    // 16-atom component sums across the quad (4 scalar DPP butterflies)
    float g0 = quad_sum(gs01.x), g1 = quad_sum(gs01.y);
    float g2 = quad_sum(gs23.x), g3 = quad_sum(gs23.y);

    // this lane's gate only (weights pre-scaled by -LOG2E/16), then share
    float tl = gbp + w0 * g0 + w1 * g1 + w2 * g2 + w3 * g3;
    float gown = __builtin_amdgcn_rcpf(1.f + __builtin_amdgcn_exp2f(tl));
    float gx = quad_bcast<0x00>(gown);
    float gy = quad_bcast<0x55>(gown);
    float gz = quad_bcast<0xAA>(gown);
    float gw_ = quad_bcast<0xFF>(gown);
    f32x2 gA = (f32x2){gx, gy}, gB = (f32x2){gz, gw_};

    #pragma unroll
    for (int a = 0; a < 4; ++a) {
      f32x2 sA = h01[a] * gA;            // (sx, sy)
      f32x2 sB = h23[a] * gB;            // (sz, sw)
      float4 vq = *(const float4*)&vt[jj][ag * 16 + a * 4];
      f32x2 v01 = (f32x2){vq.x, vq.y}, v23 = (f32x2){vq.z, vq.w};
      f32x2 sv01 = (f32x2){vq.y, vq.x}, sv23 = (f32x2){vq.w, vq.z};
      f32x2 sx2 = (f32x2){sA.x, sA.x}, sy2 = (f32x2){sA.y, sA.y};
      f32x2 sz2 = (f32x2){sB.x, sB.x}, sw2 = (f32x2){sB.y, sB.y};
      // o01 += sx*(vx,vy) + sy*(-vy,vx) + sz*(-vz,vw) + sw*(-vw,-vz)
      c01[a] += sx2 * v01;
      c01[a] += sy2 * (f32x2){-sv01.x, sv01.y};
      c01[a] += sz2 * (f32x2){-v23.x, v23.y};
      c01[a] += sw2 * (f32x2){-sv23.x, -sv23.y};
      // o23 += sx*(vz,vw) + sy*(-vw,vz) + sz*(vx,-vy) + sw*(vy,vx)
      c23[a] += sx2 * v23;
      c23[a] += sy2 * (f32x2){-sv23.x, sv23.y};
      c23[a] += sz2 * (f32x2){v01.x, -v01.y};
      c23[a] += sw2 * sv01;
    }
  }

  // plain stores into this j-chunk's slab
  float* cp = CTXS + ((size_t)(js * NBH + bh) * L_SEQ + i) * HD + ag * 16;
  #pragma unroll
  for (int t = 0; t < 4; ++t) {
    float4 o = make_float4(c01[t].x, c01[t].y, c23[t].x, c23[t].y);
    ((float4*)cp)[t] = o;
  }
}

// ---------------------------------------------------------------------------
// Sum the JSPLIT ctx slabs, transpose heads into (b,l,e), emit bf16 (R5).
// ---------------------------------------------------------------------------
__global__ __launch_bounds__(256) void ctx_reduce(
    const float* __restrict__ CTXS, unsigned short* __restrict__ CTXB)
{
  int idx = blockIdx.x * 256 + threadIdx.x;      // over 98304 float4 groups
  int row = idx >> 4;                            // bh*L + i
  int d0 = (idx & 15) * 4;
  float4 s = make_float4(0.f, 0.f, 0.f, 0.f);
  #pragma unroll
  for (int js = 0; js < JSPLIT; ++js) {
    float4 v = *(const float4*)&CTXS[(size_t)js * PROJ_ELEMS + (size_t)row * HD + d0];
    s.x += v.x; s.y += v.y; s.z += v.z; s.w += v.w;
  }
  int bh = row / L_SEQ, i = row - bh * L_SEQ;
  int b = bh >> 3, h = bh & 7;
  unsigned lo = f2bf(s.x) | (f2bf(s.y) << 16);
  unsigned hi = f2bf(s.z) | (f2bf(s.w) << 16);
  *(uint2*)&CTXB[((size_t)(b * L_SEQ + i) * E_DIM) + h * HD + d0] = make_uint2(lo, hi);
}

// ---------------------------------------------------------------------------
// Workspace (R5-proven layout, 24,379,392 B):
//   [0          .. 1572864)  Qw fp32            | CTXB bf16 (after berry)
//   [1572864    .. 3145728)  Kw fp32
//   [3145728    .. 4718592)  Vw fp32
//   [4718592    .. 23592960) CTXS (12 slabs)    | xb|Wqb|Wkb|Wvb bf16 (pre-berry)
//   [23592960   .. 24117248) Wob bf16
// ---------------------------------------------------------------------------
extern "C" void kernel_launch(void* const* d_in, const int* in_sizes, int n_in,
                              void* d_out, int out_size, void* d_ws, size_t ws_size,
                              hipStream_t stream)
{
  const float* x     = (const float*)d_in[0];
  const float* Wq    = (const float*)d_in[1];
  const float* Wk    = (const float*)d_in[2];
  const float* Wv    = (const float*)d_in[3];
  const float* Wo    = (const float*)d_in[4];
  const float* dde_w = (const float*)d_in[5];
  const float* dde_b = (const float*)d_in[6];
  float* out = (float*)d_out;

  char* ws = (char*)d_ws;
  float* Qw   = (float*)(ws + 0);
  float* Kw   = (float*)(ws + 1572864);
  float* Vw   = (float*)(ws + 3145728);
  float* CTXS = (float*)(ws + 4718592);
  unsigned short* xb   = (unsigned short*)(ws + 4718592);   // dead before berry
  unsigned short* Wqb  = (unsigned short*)(ws + 5505024);
  unsigned short* Wkb  = (unsigned short*)(ws + 6029312);
  unsigned short* Wvb  = (unsigned short*)(ws + 6553600);
  unsigned short* Wob  = (unsigned short*)(ws + 23592960);
  unsigned short* CTXB = (unsigned short*)(ws + 0);         // born after Qw dead

  // 1) fp32 -> bf16 conversions
  to_bf16_all<<<1408, 256, 0, stream>>>(x, Wq, Wk, Wv, Wo, xb, Wob);

  // 2) Q/K/V projections: pure-bf16 MFMA, head-scatter fp32 epilogue
  gemm_mfma<<<dim3(8, 12, 3), 256, 0, stream>>>(
      (const __bf16*)xb, (const __bf16*)Wqb, (const __bf16*)Wkb, (const __bf16*)Wvb,
      Qw, Kw, Vw, 2 * L_SEQ, E_DIM, E_DIM, 1);

  // 3) fused pairwise core -> 12 fp32 slabs
  berry_main<<<dim3(JSPLIT, 12, NBH), 128, 0, stream>>>(
      Qw, Kw, Vw, dde_w, dde_b, CTXS);

  // 4) slab reduction + head transpose -> bf16
  ctx_reduce<<<384, 256, 0, stream>>>(CTXS, CTXB);

  // 5) output projection: pure-bf16 MFMA, fp32 out
  gemm_mfma<<<dim3(8, 12, 1), 256, 0, stream>>>(
      (const __bf16*)CTXB, (const __bf16*)Wob, nullptr, nullptr,
      out, nullptr, nullptr, 2 * L_SEQ, E_DIM, E_DIM, 0);
}